// Round 2
// baseline (1626.459 us; speedup 1.0000x reference)
//
#include <hip/hip_runtime.h>
#include <math.h>

// Problem constants
#define BB 8
#define NN 4096
#define CC 96
#define C2 192
#define NP 1024
#define NS 16

// ws layout (bytes)
#define SAMP_OFF   0u           // int[8*1024]            32768
#define NBR_OFF    32768u       // int[8*1024*16]        524288
#define WSW_OFF    655360u      // float[384*96]         147456
#define B1_OFF     802816u      // float[192]               768
#define WCT_OFF    803584u      // float[192*192]        147456
#define B2_OFF     951040u      // float[192]               768
#define ZT_OFF     958464u      // float[8*4096*384]   50331648
// total ~51.3 MB

// ---------------------------------------------------------------------------
// prep: fold BN scale into weights; beta = b - m*s ; WcT transposed
// ---------------------------------------------------------------------------
__global__ void prep_kernel(const float* __restrict__ Wt, const float* __restrict__ gt,
                            const float* __restrict__ bt, const float* __restrict__ mt,
                            const float* __restrict__ vt, const float* __restrict__ Wc,
                            const float* __restrict__ gc, const float* __restrict__ bc,
                            const float* __restrict__ mc, const float* __restrict__ vc,
                            float* __restrict__ Ws, float* __restrict__ beta1,
                            float* __restrict__ WcT, float* __restrict__ beta2) {
    int i = blockIdx.x * blockDim.x + threadIdx.x;
    if (i < C2) {
        float s1 = gt[i] / sqrtf(vt[i] + 1e-5f);
        beta1[i] = bt[i] - mt[i] * s1;
        float s2 = gc[i] / sqrtf(vc[i] + 1e-5f);
        beta2[i] = bc[i] - mc[i] * s2;
    }
    if (i < 384 * 96) {
        int r = i / 96, c = i - r * 96;
        int o = (r < C2) ? r : r - C2;
        float s1 = gt[o] / sqrtf(vt[o] + 1e-5f);
        float w = (r < C2) ? Wt[o * C2 + c] : Wt[o * C2 + 96 + c];
        Ws[i] = w * s1;
    }
    if (i < C2 * C2) {
        int o = i / C2, c = i - o * C2;
        float s2 = gc[o] / sqrtf(vc[o] + 1e-5f);
        WcT[c * C2 + o] = Wc[i] * s2;
    }
}

// ---------------------------------------------------------------------------
// FPS: one block per batch, 512 threads, 8 points/thread held in registers.
// Exact arithmetic: ((dx*dx + dy*dy) + dz*dz) with _rn intrinsics (no FMA),
// argmax with first-index tie-break, matching np/jnp.argmax (f32).
// Writes new_p (f32) directly into d_out[0 .. 24576).
// ---------------------------------------------------------------------------
__global__ __launch_bounds__(512) void fps_kernel(const float* __restrict__ p,
                                                  int* __restrict__ samp,
                                                  float* __restrict__ out) {
    int b = blockIdx.x;
    const float* pb = p + (size_t)b * NN * 3;
    __shared__ float sx[NN], sy[NN], sz[NN];
    __shared__ float redv[8];
    __shared__ int   redi[8];
    int tid = threadIdx.x;

    float px[8], py[8], pz[8], mind[8];
    for (int i = 0; i < 8; ++i) {
        int j = tid + i * 512;
        float a = pb[j * 3 + 0];
        float c = pb[j * 3 + 1];
        float d = pb[j * 3 + 2];
        px[i] = a; py[i] = c; pz[i] = d;
        mind[i] = 1e10f;
        sx[j] = a; sy[j] = c; sz[j] = d;
    }
    __syncthreads();

    int last = 0;
    float lx = sx[0], ly = sy[0], lz = sz[0];

    for (int it = 0; it < NP; ++it) {
        if (tid == 0) {
            samp[b * NP + it] = last;
            size_t o3 = ((size_t)b * NP + it) * 3;
            out[o3 + 0] = lx; out[o3 + 1] = ly; out[o3 + 2] = lz;
        }
        float bv = -1.0f; int bi = 0;
        for (int i = 0; i < 8; ++i) {
            float dx = __fsub_rn(px[i], lx);
            float dy = __fsub_rn(py[i], ly);
            float dz = __fsub_rn(pz[i], lz);
            float d = __fadd_rn(__fadd_rn(__fmul_rn(dx, dx), __fmul_rn(dy, dy)),
                                __fmul_rn(dz, dz));
            float m = fminf(mind[i], d);
            mind[i] = m;
            int j = tid + i * 512;
            bool take = (m > bv) || (m == bv && j < bi);
            bv = take ? m : bv;
            bi = take ? j : bi;
        }
        // wave reduce (64 lanes), min index among maxima
        for (int off = 32; off; off >>= 1) {
            float ov = __shfl_xor(bv, off, 64);
            int oi = __shfl_xor(bi, off, 64);
            bool take = (ov > bv) || (ov == bv && oi < bi);
            bv = take ? ov : bv;
            bi = take ? oi : bi;
        }
        if ((tid & 63) == 0) { redv[tid >> 6] = bv; redi[tid >> 6] = bi; }
        __syncthreads();
        bv = redv[0]; bi = redi[0];
        for (int w = 1; w < 8; ++w) {
            float ov = redv[w]; int oi = redi[w];
            bool take = (ov > bv) || (ov == bv && oi < bi);
            bv = take ? ov : bv;
            bi = take ? oi : bi;
        }
        last = bi;
        lx = sx[bi]; ly = sy[bi]; lz = sz[bi];
        __syncthreads();   // protect redv/redi reuse next iteration
    }
}

// ---------------------------------------------------------------------------
// Ball query: one wave per center. Ballot per 64-point chunk, take first-16
// set bits in index order; pad with first found. Threshold 0.01f matches
// f32(0.01) used by the reference comparison.
// ---------------------------------------------------------------------------
__global__ __launch_bounds__(256) void ballquery_kernel(const float* __restrict__ p,
                                                        const float* __restrict__ newp,
                                                        int* __restrict__ nbr) {
    __shared__ float sx[NN], sy[NN], sz[NN];
    int blk = blockIdx.x;              // 2048 blocks, 256 per batch
    int b = blk >> 8;
    int tid = threadIdx.x;
    const float* pb = p + (size_t)b * NN * 3;
    for (int idx = tid; idx < NN; idx += 256) {
        sx[idx] = pb[idx * 3 + 0];
        sy[idx] = pb[idx * 3 + 1];
        sz[idx] = pb[idx * 3 + 2];
    }
    __syncthreads();
    int wave = tid >> 6, lane = tid & 63;
    int g = (blk & 255) * 4 + wave;    // 0..1023
    int gidx = b * NP + g;
    float cx = newp[(size_t)gidx * 3 + 0];
    float cy = newp[(size_t)gidx * 3 + 1];
    float cz = newp[(size_t)gidx * 3 + 2];
    const float R2 = 0.01f;
    int cnt = 0, first = -1;
    for (int chunk = 0; chunk < NN / 64 && cnt < NS; ++chunk) {
        int j = chunk * 64 + lane;
        float dx = __fsub_rn(cx, sx[j]);
        float dy = __fsub_rn(cy, sy[j]);
        float dz = __fsub_rn(cz, sz[j]);
        float d2 = __fadd_rn(__fadd_rn(__fmul_rn(dx, dx), __fmul_rn(dy, dy)),
                             __fmul_rn(dz, dz));
        unsigned long long mask = __ballot(d2 < R2);
        while (mask && cnt < NS) {
            int bit = __ffsll(mask) - 1;
            mask &= mask - 1;
            int idx = chunk * 64 + bit;
            if (first < 0) first = idx;
            if (lane == 0) nbr[(size_t)gidx * NS + cnt] = idx;
            ++cnt;
        }
    }
    if (lane == 0) {
        for (int i = cnt; i < NS; ++i) nbr[(size_t)gidx * NS + i] = first;
    }
}

// ---------------------------------------------------------------------------
// GEMM1: zt[b][j][384] = Ws[384x96] @ relu(x[b][:, j]).
// rows 0..191 = center-part (Wt[:, :96]*s1), 192..383 = neighbor-part.
// ---------------------------------------------------------------------------
__global__ __launch_bounds__(256) void gemm1_kernel(const float* __restrict__ x,
                                                    const float* __restrict__ Ws,
                                                    float* __restrict__ zt) {
    __shared__ float xt[96][64];
    __shared__ float wt[64][97];
    int jt = blockIdx.x;   // 0..63
    int ob = blockIdx.y;   // 0..5
    int b = blockIdx.z;    // 0..7
    int tid = threadIdx.x;

    for (int idx = tid; idx < 96 * 64; idx += 256) {
        int c = idx >> 6, j = idx & 63;
        xt[c][j] = fmaxf(x[((size_t)b * CC + c) * NN + jt * 64 + j], 0.0f);
    }
    for (int idx = tid; idx < 64 * 96; idx += 256) {
        int r = idx / 96, c = idx - r * 96;
        wt[r][c] = Ws[(ob * 64 + r) * 96 + c];
    }
    __syncthreads();

    int ty = tid >> 4, tx = tid & 15;
    float acc[4][4] = {};
    for (int k = 0; k < 96; ++k) {
        float a0 = wt[ty * 4 + 0][k];
        float a1 = wt[ty * 4 + 1][k];
        float a2 = wt[ty * 4 + 2][k];
        float a3 = wt[ty * 4 + 3][k];
        float4 bv = *(const float4*)&xt[k][tx * 4];
        acc[0][0] = fmaf(a0, bv.x, acc[0][0]); acc[0][1] = fmaf(a0, bv.y, acc[0][1]);
        acc[0][2] = fmaf(a0, bv.z, acc[0][2]); acc[0][3] = fmaf(a0, bv.w, acc[0][3]);
        acc[1][0] = fmaf(a1, bv.x, acc[1][0]); acc[1][1] = fmaf(a1, bv.y, acc[1][1]);
        acc[1][2] = fmaf(a1, bv.z, acc[1][2]); acc[1][3] = fmaf(a1, bv.w, acc[1][3]);
        acc[2][0] = fmaf(a2, bv.x, acc[2][0]); acc[2][1] = fmaf(a2, bv.y, acc[2][1]);
        acc[2][2] = fmaf(a2, bv.z, acc[2][2]); acc[2][3] = fmaf(a2, bv.w, acc[2][3]);
        acc[3][0] = fmaf(a3, bv.x, acc[3][0]); acc[3][1] = fmaf(a3, bv.y, acc[3][1]);
        acc[3][2] = fmaf(a3, bv.z, acc[3][2]); acc[3][3] = fmaf(a3, bv.w, acc[3][3]);
    }
    for (int jj = 0; jj < 4; ++jj) {
        int j = jt * 64 + tx * 4 + jj;
        float4 v = make_float4(acc[0][jj], acc[1][jj], acc[2][jj], acc[3][jj]);
        *(float4*)&zt[((size_t)b * NN + j) * 384 + ob * 64 + ty * 4] = v;
    }
}

// ---------------------------------------------------------------------------
// Fused: gather zc+zn, +beta -> relu, sin/cos pos embed, agg=(t+1)*emb,
// max+mean pool, relu, 192x192 conv2 (BN folded) -> relu -> f32 store.
// 8192 blocks x 192 threads (thread = output channel).
// ---------------------------------------------------------------------------
__global__ __launch_bounds__(192) void fused_kernel(const float* __restrict__ p,
                                                    const float* __restrict__ newp,
                                                    const int* __restrict__ samp,
                                                    const int* __restrict__ nbr,
                                                    const float* __restrict__ zt,
                                                    const float* __restrict__ beta1,
                                                    const float* __restrict__ WcT,
                                                    const float* __restrict__ beta2,
                                                    float* __restrict__ out) {
    int blk = blockIdx.x;
    int b = blk >> 10, g = blk & 1023;
    int tid = threadIdx.x;
    __shared__ float dp[3][NS];
    __shared__ int nb[NS];
    __shared__ float pl[C2];

    if (tid < NS) {
        int j = nbr[(size_t)blk * NS + tid];
        nb[tid] = j;
        dp[0][tid] = p[((size_t)b * NN + j) * 3 + 0] - newp[(size_t)blk * 3 + 0];
        dp[1][tid] = p[((size_t)b * NN + j) * 3 + 1] - newp[(size_t)blk * 3 + 1];
        dp[2][tid] = p[((size_t)b * NN + j) * 3 + 2] - newp[(size_t)blk * 3 + 2];
    }
    __syncthreads();

    int o = tid;
    int sidx = samp[blk];
    float zc = zt[((size_t)b * NN + sidx) * 384 + o];
    float bet = beta1[o];
    int axis = o >> 6;        // 0..2
    int k = o & 63;
    int kk = (k < 32) ? k : k - 32;
    float dim = powf(500.0f, (float)kk * (1.0f / 32.0f));

    float mx = -3.4e38f, sm = 0.0f;
    for (int s = 0; s < NS; ++s) {
        float zn = zt[((size_t)b * NN + nb[s]) * 384 + C2 + o];
        float t = fmaxf(zc + zn + bet, 0.0f);
        float pos = (50.0f * dp[axis][s]) / dim;
        float e = (k < 32) ? sinf(pos) : cosf(pos);
        float a = fmaf(t, e, e);          // xj*emb + emb
        mx = fmaxf(mx, a);
        sm += a;
    }
    pl[o] = fmaxf(mx + sm * (1.0f / 16.0f), 0.0f);
    __syncthreads();

    float acc = 0.0f;
    for (int c = 0; c < C2; ++c) acc = fmaf(WcT[c * C2 + o], pl[c], acc);
    float res = fmaxf(acc + beta2[o], 0.0f);
    out[BB * NP * 3 + ((size_t)b * C2 + o) * NP + g] = res;
}

// ---------------------------------------------------------------------------
extern "C" void kernel_launch(void* const* d_in, const int* in_sizes, int n_in,
                              void* d_out, int out_size, void* d_ws, size_t ws_size,
                              hipStream_t stream) {
    (void)in_sizes; (void)n_in; (void)out_size; (void)ws_size;
    const float* p  = (const float*)d_in[0];
    const float* x  = (const float*)d_in[1];
    const float* Wt = (const float*)d_in[2];
    const float* gt = (const float*)d_in[3];
    const float* bt = (const float*)d_in[4];
    const float* mt = (const float*)d_in[5];
    const float* vt = (const float*)d_in[6];
    const float* Wc = (const float*)d_in[7];
    const float* gc = (const float*)d_in[8];
    const float* bc = (const float*)d_in[9];
    const float* mc = (const float*)d_in[10];
    const float* vc = (const float*)d_in[11];
    float* out = (float*)d_out;              // f32 output (reference is all-f32)
    char* ws = (char*)d_ws;

    int*   samp  = (int*)(ws + SAMP_OFF);
    int*   nbr   = (int*)(ws + NBR_OFF);
    float* Ws    = (float*)(ws + WSW_OFF);
    float* beta1 = (float*)(ws + B1_OFF);
    float* WcT   = (float*)(ws + WCT_OFF);
    float* beta2 = (float*)(ws + B2_OFF);
    float* zt    = (float*)(ws + ZT_OFF);
    const float* newp = out;                 // new_p lives in d_out[0 .. 24576)

    prep_kernel<<<dim3(145), dim3(256), 0, stream>>>(Wt, gt, bt, mt, vt,
                                                     Wc, gc, bc, mc, vc,
                                                     Ws, beta1, WcT, beta2);
    fps_kernel<<<dim3(BB), dim3(512), 0, stream>>>(p, samp, out);
    ballquery_kernel<<<dim3(2048), dim3(256), 0, stream>>>(p, newp, nbr);
    gemm1_kernel<<<dim3(64, 6, 8), dim3(256), 0, stream>>>(x, Ws, zt);
    fused_kernel<<<dim3(BB * NP), dim3(192), 0, stream>>>(p, newp, samp, nbr, zt,
                                                          beta1, WcT, beta2, out);
}

// Round 3
// 974.061 us; speedup vs baseline: 1.6698x; 1.6698x over previous
//
#include <hip/hip_runtime.h>
#include <math.h>

// Problem constants
#define BB 8
#define NN 4096
#define CC 96
#define C2 192
#define NP 1024
#define NS 16
#define PPT 16   // points per thread in FPS (256 threads * 16 = 4096)

// ws layout (bytes)
#define SAMP_OFF   0u           // int[8*1024]            32768
#define NBR_OFF    32768u       // int[8*1024*16]        524288
#define WSW_OFF    655360u      // float[384*96]         147456
#define B1_OFF     802816u      // float[192]               768
#define WCT_OFF    803584u      // float[192*192]        147456
#define B2_OFF     951040u      // float[192]               768
#define ZT_OFF     958464u      // float[8*4096*384]   50331648

// ---------------------------------------------------------------------------
// Launch 1: blocks 0..7 = FPS (one per batch); blocks 8..152 = prep.
// FPS: 256 threads, 16 pts/thread in registers. Exact reference arithmetic:
// ((dx*dx + dy*dy) + dz*dz) with _rn intrinsics (no FMA). Argmax via packed
// u64 key (f32bits(mind) << 32) | (4095 - j): max == largest dist, first
// index on ties (matches np.argmax). Writes new_p (f32) into d_out[0..24576).
// ---------------------------------------------------------------------------
__global__ __launch_bounds__(256) void fps_prep_kernel(
        const float* __restrict__ p,
        const float* __restrict__ Wt, const float* __restrict__ gt,
        const float* __restrict__ bt, const float* __restrict__ mt,
        const float* __restrict__ vt, const float* __restrict__ Wc,
        const float* __restrict__ gc, const float* __restrict__ bc,
        const float* __restrict__ mc, const float* __restrict__ vc,
        float* __restrict__ Ws, float* __restrict__ beta1,
        float* __restrict__ WcT, float* __restrict__ beta2,
        int* __restrict__ samp, float* __restrict__ out) {
    if (blockIdx.x >= BB) {
        // ---- prep: fold BN scale into weights ----
        int i = (blockIdx.x - BB) * 256 + threadIdx.x;
        if (i < C2) {
            float s1 = gt[i] / sqrtf(vt[i] + 1e-5f);
            beta1[i] = bt[i] - mt[i] * s1;
            float s2 = gc[i] / sqrtf(vc[i] + 1e-5f);
            beta2[i] = bc[i] - mc[i] * s2;
        }
        if (i < 384 * 96) {
            int r = i / 96, c = i - r * 96;
            int o = (r < C2) ? r : r - C2;
            float s1 = gt[o] / sqrtf(vt[o] + 1e-5f);
            float w = (r < C2) ? Wt[o * C2 + c] : Wt[o * C2 + 96 + c];
            Ws[i] = w * s1;
        }
        if (i < C2 * C2) {
            int o = i / C2, c = i - o * C2;
            float s2 = gc[o] / sqrtf(vc[o] + 1e-5f);
            WcT[c * C2 + o] = Wc[i] * s2;
        }
        return;
    }
    // ---- FPS ----
    int b = blockIdx.x;
    const float* pb = p + (size_t)b * NN * 3;
    __shared__ float sx[NN], sy[NN], sz[NN];
    __shared__ unsigned long long redk[2][4];
    int tid = threadIdx.x;

    float px[PPT], py[PPT], pz[PPT], mind[PPT];
    int jbase = tid * PPT;
    for (int i = 0; i < PPT; ++i) {
        int j = jbase + i;
        float a = pb[j * 3 + 0];
        float c = pb[j * 3 + 1];
        float d = pb[j * 3 + 2];
        px[i] = a; py[i] = c; pz[i] = d;
        mind[i] = 1e10f;
        sx[j] = a; sy[j] = c; sz[j] = d;
    }
    __syncthreads();

    int last = 0;
    float lx = sx[0], ly = sy[0], lz = sz[0];
    unsigned inv_base = 4095u - (unsigned)jbase;

    for (int it = 0; it < NP; ++it) {
        if (tid == 0) {
            samp[b * NP + it] = last;
            size_t o3 = ((size_t)b * NP + it) * 3;
            out[o3 + 0] = lx; out[o3 + 1] = ly; out[o3 + 2] = lz;
        }
        unsigned long long key = 0ull;
        #pragma unroll
        for (int i = 0; i < PPT; ++i) {
            float dx = __fsub_rn(px[i], lx);
            float dy = __fsub_rn(py[i], ly);
            float dz = __fsub_rn(pz[i], lz);
            float d = __fadd_rn(__fadd_rn(__fmul_rn(dx, dx), __fmul_rn(dy, dy)),
                                __fmul_rn(dz, dz));
            float m = fminf(mind[i], d);
            mind[i] = m;
            unsigned long long k =
                ((unsigned long long)__float_as_uint(m) << 32) | (unsigned long long)(inv_base - i);
            key = (k > key) ? k : key;
        }
        // wave butterfly (6 steps) — all lanes end with wave max
        #pragma unroll
        for (int off = 1; off < 64; off <<= 1) {
            unsigned long long o = __shfl_xor(key, off, 64);
            key = (o > key) ? o : key;
        }
        if ((tid & 63) == 0) redk[it & 1][tid >> 6] = key;
        __syncthreads();
        unsigned long long k0 = redk[it & 1][0], k1 = redk[it & 1][1];
        unsigned long long k2 = redk[it & 1][2], k3 = redk[it & 1][3];
        k0 = (k1 > k0) ? k1 : k0;
        k2 = (k3 > k2) ? k3 : k2;
        k0 = (k2 > k0) ? k2 : k0;
        int bi = 4095 - (int)(unsigned)(k0 & 0xffffffffull);
        last = bi;
        lx = sx[bi]; ly = sy[bi]; lz = sz[bi];
        // no second barrier: redk is double-buffered (WAR separated by next barrier)
    }
}

// ---------------------------------------------------------------------------
// Launch 2: blocks 0..2047 = ball query; blocks 2048..5119 = GEMM1.
// Shared LDS aliased through one array (ballquery 12288 floats, gemm 12352).
// ---------------------------------------------------------------------------
__global__ __launch_bounds__(256) void bq_gemm_kernel(
        const float* __restrict__ p, const float* __restrict__ newp,
        int* __restrict__ nbr,
        const float* __restrict__ x, const float* __restrict__ Ws,
        float* __restrict__ zt) {
    __shared__ float smem[12352];
    int tid = threadIdx.x;

    if (blockIdx.x < 2048) {
        // ---- ball query: one wave per center ----
        float* sx = smem;
        float* sy = smem + NN;
        float* sz = smem + 2 * NN;
        int blk = blockIdx.x;
        int b = blk >> 8;
        const float* pb = p + (size_t)b * NN * 3;
        for (int idx = tid; idx < NN; idx += 256) {
            sx[idx] = pb[idx * 3 + 0];
            sy[idx] = pb[idx * 3 + 1];
            sz[idx] = pb[idx * 3 + 2];
        }
        __syncthreads();
        int wave = tid >> 6, lane = tid & 63;
        int g = (blk & 255) * 4 + wave;    // 0..1023
        int gidx = b * NP + g;
        float cx = newp[(size_t)gidx * 3 + 0];
        float cy = newp[(size_t)gidx * 3 + 1];
        float cz = newp[(size_t)gidx * 3 + 2];
        const float R2 = 0.01f;
        int cnt = 0, first = -1;
        for (int chunk = 0; chunk < NN / 64 && cnt < NS; ++chunk) {
            int j = chunk * 64 + lane;
            float dx = __fsub_rn(cx, sx[j]);
            float dy = __fsub_rn(cy, sy[j]);
            float dz = __fsub_rn(cz, sz[j]);
            float d2 = __fadd_rn(__fadd_rn(__fmul_rn(dx, dx), __fmul_rn(dy, dy)),
                                 __fmul_rn(dz, dz));
            unsigned long long mask = __ballot(d2 < R2);
            while (mask && cnt < NS) {
                int bit = __ffsll(mask) - 1;
                mask &= mask - 1;
                int idx = chunk * 64 + bit;
                if (first < 0) first = idx;
                if (lane == 0) nbr[(size_t)gidx * NS + cnt] = idx;
                ++cnt;
            }
        }
        if (lane == 0) {
            for (int i = cnt; i < NS; ++i) nbr[(size_t)gidx * NS + i] = first;
        }
    } else {
        // ---- GEMM1: zt[b][j][384] = Ws[384x96] @ relu(x[b][:, j]) ----
        float* xt = smem;            // [96][64]
        float* wt = smem + 6144;     // [64][97]
        int g = blockIdx.x - 2048;
        int b = g & 7;
        int t2 = g >> 3;             // 0..383
        int ob = t2 >> 6;            // 0..5
        int jt = t2 & 63;            // 0..63

        for (int idx = tid; idx < 96 * 64; idx += 256) {
            int c = idx >> 6, j = idx & 63;
            xt[c * 64 + j] = fmaxf(x[((size_t)b * CC + c) * NN + jt * 64 + j], 0.0f);
        }
        for (int idx = tid; idx < 64 * 96; idx += 256) {
            int r = idx / 96, c = idx - r * 96;
            wt[r * 97 + c] = Ws[(ob * 64 + r) * 96 + c];
        }
        __syncthreads();

        int ty = tid >> 4, tx = tid & 15;
        float acc[4][4] = {};
        for (int k = 0; k < 96; ++k) {
            float a0 = wt[(ty * 4 + 0) * 97 + k];
            float a1 = wt[(ty * 4 + 1) * 97 + k];
            float a2 = wt[(ty * 4 + 2) * 97 + k];
            float a3 = wt[(ty * 4 + 3) * 97 + k];
            float4 bv = *(const float4*)&xt[k * 64 + tx * 4];
            acc[0][0] = fmaf(a0, bv.x, acc[0][0]); acc[0][1] = fmaf(a0, bv.y, acc[0][1]);
            acc[0][2] = fmaf(a0, bv.z, acc[0][2]); acc[0][3] = fmaf(a0, bv.w, acc[0][3]);
            acc[1][0] = fmaf(a1, bv.x, acc[1][0]); acc[1][1] = fmaf(a1, bv.y, acc[1][1]);
            acc[1][2] = fmaf(a1, bv.z, acc[1][2]); acc[1][3] = fmaf(a1, bv.w, acc[1][3]);
            acc[2][0] = fmaf(a2, bv.x, acc[2][0]); acc[2][1] = fmaf(a2, bv.y, acc[2][1]);
            acc[2][2] = fmaf(a2, bv.z, acc[2][2]); acc[2][3] = fmaf(a2, bv.w, acc[2][3]);
            acc[3][0] = fmaf(a3, bv.x, acc[3][0]); acc[3][1] = fmaf(a3, bv.y, acc[3][1]);
            acc[3][2] = fmaf(a3, bv.z, acc[3][2]); acc[3][3] = fmaf(a3, bv.w, acc[3][3]);
        }
        for (int jj = 0; jj < 4; ++jj) {
            int j = jt * 64 + tx * 4 + jj;
            float4 v = make_float4(acc[0][jj], acc[1][jj], acc[2][jj], acc[3][jj]);
            *(float4*)&zt[((size_t)b * NN + j) * 384 + ob * 64 + ty * 4] = v;
        }
    }
}

// ---------------------------------------------------------------------------
// Fused: gather zc+zn, +beta -> relu, sin/cos pos embed, agg=(t+1)*emb,
// max+mean pool, relu, 192x192 conv2 (BN folded) -> relu -> f32 store.
// ---------------------------------------------------------------------------
__global__ __launch_bounds__(192) void fused_kernel(const float* __restrict__ p,
                                                    const float* __restrict__ newp,
                                                    const int* __restrict__ samp,
                                                    const int* __restrict__ nbr,
                                                    const float* __restrict__ zt,
                                                    const float* __restrict__ beta1,
                                                    const float* __restrict__ WcT,
                                                    const float* __restrict__ beta2,
                                                    float* __restrict__ out) {
    int blk = blockIdx.x;
    int b = blk >> 10, g = blk & 1023;
    int tid = threadIdx.x;
    __shared__ float dp[3][NS];
    __shared__ int nb[NS];
    __shared__ float pl[C2];

    if (tid < NS) {
        int j = nbr[(size_t)blk * NS + tid];
        nb[tid] = j;
        dp[0][tid] = p[((size_t)b * NN + j) * 3 + 0] - newp[(size_t)blk * 3 + 0];
        dp[1][tid] = p[((size_t)b * NN + j) * 3 + 1] - newp[(size_t)blk * 3 + 1];
        dp[2][tid] = p[((size_t)b * NN + j) * 3 + 2] - newp[(size_t)blk * 3 + 2];
    }
    __syncthreads();

    int o = tid;
    int sidx = samp[blk];
    float zc = zt[((size_t)b * NN + sidx) * 384 + o];
    float bet = beta1[o];
    int axis = o >> 6;        // 0..2
    int k = o & 63;
    int kk = (k < 32) ? k : k - 32;
    float dim = powf(500.0f, (float)kk * (1.0f / 32.0f));

    float mx = -3.4e38f, sm = 0.0f;
    for (int s = 0; s < NS; ++s) {
        float zn = zt[((size_t)b * NN + nb[s]) * 384 + C2 + o];
        float t = fmaxf(zc + zn + bet, 0.0f);
        float pos = (50.0f * dp[axis][s]) / dim;
        float e = (k < 32) ? sinf(pos) : cosf(pos);
        float a = fmaf(t, e, e);          // xj*emb + emb
        mx = fmaxf(mx, a);
        sm += a;
    }
    pl[o] = fmaxf(mx + sm * (1.0f / 16.0f), 0.0f);
    __syncthreads();

    float acc = 0.0f;
    for (int c = 0; c < C2; ++c) acc = fmaf(WcT[c * C2 + o], pl[c], acc);
    float res = fmaxf(acc + beta2[o], 0.0f);
    out[BB * NP * 3 + ((size_t)b * C2 + o) * NP + g] = res;
}

// ---------------------------------------------------------------------------
extern "C" void kernel_launch(void* const* d_in, const int* in_sizes, int n_in,
                              void* d_out, int out_size, void* d_ws, size_t ws_size,
                              hipStream_t stream) {
    (void)in_sizes; (void)n_in; (void)out_size; (void)ws_size;
    const float* p  = (const float*)d_in[0];
    const float* x  = (const float*)d_in[1];
    const float* Wt = (const float*)d_in[2];
    const float* gt = (const float*)d_in[3];
    const float* bt = (const float*)d_in[4];
    const float* mt = (const float*)d_in[5];
    const float* vt = (const float*)d_in[6];
    const float* Wc = (const float*)d_in[7];
    const float* gc = (const float*)d_in[8];
    const float* bc = (const float*)d_in[9];
    const float* mc = (const float*)d_in[10];
    const float* vc = (const float*)d_in[11];
    float* out = (float*)d_out;              // f32 output (reference is all-f32)
    char* ws = (char*)d_ws;

    int*   samp  = (int*)(ws + SAMP_OFF);
    int*   nbr   = (int*)(ws + NBR_OFF);
    float* Ws    = (float*)(ws + WSW_OFF);
    float* beta1 = (float*)(ws + B1_OFF);
    float* WcT   = (float*)(ws + WCT_OFF);
    float* beta2 = (float*)(ws + B2_OFF);
    float* zt    = (float*)(ws + ZT_OFF);
    const float* newp = out;                 // new_p lives in d_out[0 .. 24576)

    fps_prep_kernel<<<dim3(BB + 145), dim3(256), 0, stream>>>(
        p, Wt, gt, bt, mt, vt, Wc, gc, bc, mc, vc,
        Ws, beta1, WcT, beta2, samp, out);
    bq_gemm_kernel<<<dim3(2048 + 3072), dim3(256), 0, stream>>>(
        p, newp, nbr, x, Ws, zt);
    fused_kernel<<<dim3(BB * NP), dim3(192), 0, stream>>>(
        p, newp, samp, nbr, zt, beta1, WcT, beta2, out);
}

// Round 5
// 971.070 us; speedup vs baseline: 1.6749x; 1.0031x over previous
//
#include <hip/hip_runtime.h>
#include <math.h>

// Problem constants
#define BB 8
#define NN 4096
#define CC 96
#define C2 192
#define NP 1024
#define NS 16
#define PPT 16   // points per thread in FPS (256 threads * 16 = 4096)

typedef float v2f __attribute__((ext_vector_type(2)));

// ws layout (bytes)
#define SAMP_OFF   0u           // int[8*1024]            32768
#define NBR_OFF    32768u       // int[8*1024*16]        524288
#define WSW_OFF    655360u      // float[384*96]         147456
#define B1_OFF     802816u      // float[192]               768
#define WCT_OFF    803584u      // float[192*192]        147456
#define B2_OFF     951040u      // float[192]               768
#define ZT_OFF     958464u      // float[8*4096*384]   50331648

// 64-bit DPP move (per-half), old=0 identity for nonneg max keys
template<int CTRL, int RM>
__device__ __forceinline__ unsigned long long dpp_mov64(unsigned long long k) {
    int tlo = __builtin_amdgcn_update_dpp(0, (int)(unsigned)(k & 0xffffffffull),
                                          CTRL, RM, 0xf, false);
    int thi = __builtin_amdgcn_update_dpp(0, (int)(unsigned)(k >> 32),
                                          CTRL, RM, 0xf, false);
    return ((unsigned long long)(unsigned)thi << 32) | (unsigned)tlo;
}

// ---------------------------------------------------------------------------
// Launch 1: blocks 0..7 = FPS (one per batch); blocks 8..152 = prep.
// FPS: 256 threads, 16 pts/thread in registers. Exact reference arithmetic:
// ((dx*dx + dy*dy) + dz*dz), f32 rn, contraction OFF. Argmax via packed u64
// key (f32bits(mind) << 32) | (4095 - j): max == largest dist, first index
// on ties (matches np.argmax). Wave reduce via DPP (VALU-latency), cross-
// wave via 1 barrier + LDS. Writes new_p (f32) into d_out[0..24576).
// ---------------------------------------------------------------------------
__global__ __launch_bounds__(256) void fps_prep_kernel(
        const float* __restrict__ p,
        const float* __restrict__ Wt, const float* __restrict__ gt,
        const float* __restrict__ bt, const float* __restrict__ mt,
        const float* __restrict__ vt, const float* __restrict__ Wc,
        const float* __restrict__ gc, const float* __restrict__ bc,
        const float* __restrict__ mc, const float* __restrict__ vc,
        float* __restrict__ Ws, float* __restrict__ beta1,
        float* __restrict__ WcT, float* __restrict__ beta2,
        int* __restrict__ samp, float* __restrict__ out) {
    if (blockIdx.x >= BB) {
        // ---- prep: fold BN scale into weights ----
        int i = (blockIdx.x - BB) * 256 + threadIdx.x;
        if (i < C2) {
            float s1 = gt[i] / sqrtf(vt[i] + 1e-5f);
            beta1[i] = bt[i] - mt[i] * s1;
            float s2 = gc[i] / sqrtf(vc[i] + 1e-5f);
            beta2[i] = bc[i] - mc[i] * s2;
        }
        if (i < 384 * 96) {
            int r = i / 96, c = i - r * 96;
            int o = (r < C2) ? r : r - C2;
            float s1 = gt[o] / sqrtf(vt[o] + 1e-5f);
            float w = (r < C2) ? Wt[o * C2 + c] : Wt[o * C2 + 96 + c];
            Ws[i] = w * s1;
        }
        if (i < C2 * C2) {
            int o = i / C2, c = i - o * C2;
            float s2 = gc[o] / sqrtf(vc[o] + 1e-5f);
            WcT[c * C2 + o] = Wc[i] * s2;
        }
        return;
    }
    // ---- FPS ----
    {
#pragma clang fp contract(off)
    int b = blockIdx.x;
    const float* pb = p + (size_t)b * NN * 3;
    __shared__ float2 sxy[NN];                  // 32 KB
    __shared__ float  szz[NN];                  // 16 KB
    __shared__ unsigned long long redk[2][4];
    int tid = threadIdx.x;
    int jbase = tid * PPT;

    // load 48 contiguous floats (16 points) per thread, stage to LDS
    float c48[48];
    const float4* pb4 = (const float4*)(pb + (size_t)jbase * 3);
    #pragma unroll
    for (int i = 0; i < 12; ++i) ((float4*)c48)[i] = pb4[i];
    v2f px2[8], py2[8], pz2[8], mind2[8];
    #pragma unroll
    for (int q = 0; q < 8; ++q) {
        px2[q].x = c48[6*q+0]; px2[q].y = c48[6*q+3];
        py2[q].x = c48[6*q+1]; py2[q].y = c48[6*q+4];
        pz2[q].x = c48[6*q+2]; pz2[q].y = c48[6*q+5];
        mind2[q].x = 1e10f;    mind2[q].y = 1e10f;
        sxy[jbase + 2*q]     = make_float2(c48[6*q+0], c48[6*q+1]);
        szz[jbase + 2*q]     = c48[6*q+2];
        sxy[jbase + 2*q + 1] = make_float2(c48[6*q+3], c48[6*q+4]);
        szz[jbase + 2*q + 1] = c48[6*q+5];
    }

    int last = 0;
    float lx = pb[0], ly = pb[1], lz = pb[2];

    for (int it = 0; it < NP; ++it) {
        if (tid == 0) {
            samp[b * NP + it] = last;
            size_t o3 = ((size_t)b * NP + it) * 3;
            out[o3 + 0] = lx; out[o3 + 1] = ly; out[o3 + 2] = lz;
        }
        // distance update (packed f32, contraction off)
        v2f lx2; lx2.x = lx; lx2.y = lx;
        v2f ly2; ly2.x = ly; ly2.y = ly;
        v2f lz2; lz2.x = lz; lz2.y = lz;
        float m[16];
        #pragma unroll
        for (int q = 0; q < 8; ++q) {
            v2f dx = px2[q] - lx2;
            v2f dy = py2[q] - ly2;
            v2f dz = pz2[q] - lz2;
            v2f dd = (dx * dx + dy * dy) + dz * dz;
            float m0 = fminf(mind2[q].x, dd.x);
            float m1 = fminf(mind2[q].y, dd.y);
            mind2[q].x = m0; mind2[q].y = m1;
            m[2*q] = m0; m[2*q+1] = m1;
        }
        // tournament argmax over 16 (strict > keeps lower index on ties)
        float v8[8]; int i8v[8];
        #pragma unroll
        for (int q = 0; q < 8; ++q) {
            bool t = m[2*q+1] > m[2*q];
            v8[q] = t ? m[2*q+1] : m[2*q];
            i8v[q] = t ? 2*q+1 : 2*q;
        }
        float v4[4]; int i4v[4];
        #pragma unroll
        for (int q = 0; q < 4; ++q) {
            bool t = v8[2*q+1] > v8[2*q];
            v4[q] = t ? v8[2*q+1] : v8[2*q];
            i4v[q] = t ? i8v[2*q+1] : i8v[2*q];
        }
        float v2a[2]; int i2v[2];
        #pragma unroll
        for (int q = 0; q < 2; ++q) {
            bool t = v4[2*q+1] > v4[2*q];
            v2a[q] = t ? v4[2*q+1] : v4[2*q];
            i2v[q] = t ? i4v[2*q+1] : i4v[2*q];
        }
        bool tf = v2a[1] > v2a[0];
        float bv = tf ? v2a[1] : v2a[0];
        int ii  = tf ? i2v[1] : i2v[0];
        unsigned long long key =
            ((unsigned long long)__float_as_uint(bv) << 32)
            | (unsigned)(4095 - (jbase + ii));

        // wave64 max-reduce via DPP; result in lane 63
        unsigned long long t;
        t = dpp_mov64<0x111, 0xf>(key); key = (t > key) ? t : key;  // row_shr:1
        t = dpp_mov64<0x112, 0xf>(key); key = (t > key) ? t : key;  // row_shr:2
        t = dpp_mov64<0x114, 0xf>(key); key = (t > key) ? t : key;  // row_shr:4
        t = dpp_mov64<0x118, 0xf>(key); key = (t > key) ? t : key;  // row_shr:8
        t = dpp_mov64<0x142, 0xa>(key); key = (t > key) ? t : key;  // row_bcast:15
        t = dpp_mov64<0x143, 0xc>(key); key = (t > key) ? t : key;  // row_bcast:31

        if ((tid & 63) == 63) redk[it & 1][tid >> 6] = key;
        __syncthreads();
        unsigned long long k0 = redk[it & 1][0], k1 = redk[it & 1][1];
        unsigned long long k2 = redk[it & 1][2], k3 = redk[it & 1][3];
        k0 = (k1 > k0) ? k1 : k0;
        k2 = (k3 > k2) ? k3 : k2;
        k0 = (k2 > k0) ? k2 : k0;
        int bi = 4095 - (int)(unsigned)(k0 & 0xffffffffull);
        last = bi;
        float2 xy = sxy[bi];
        lx = xy.x; ly = xy.y; lz = szz[bi];
        // redk double-buffered: next write to this slot is 2 barriers away
    }
    }
}

// ---------------------------------------------------------------------------
// Launch 2: blocks 0..2047 = ball query; blocks 2048..5119 = GEMM1.
// Shared LDS aliased through one array (ballquery 12288 floats, gemm 12352).
// ---------------------------------------------------------------------------
__global__ __launch_bounds__(256) void bq_gemm_kernel(
        const float* __restrict__ p, const float* __restrict__ newp,
        int* __restrict__ nbr,
        const float* __restrict__ x, const float* __restrict__ Ws,
        float* __restrict__ zt) {
    __shared__ float smem[12352];
    int tid = threadIdx.x;

    if (blockIdx.x < 2048) {
        // ---- ball query: one wave per center ----
        float* sx = smem;
        float* sy = smem + NN;
        float* sz = smem + 2 * NN;
        int blk = blockIdx.x;
        int b = blk >> 8;
        const float* pb = p + (size_t)b * NN * 3;
        for (int idx = tid; idx < NN; idx += 256) {
            sx[idx] = pb[idx * 3 + 0];
            sy[idx] = pb[idx * 3 + 1];
            sz[idx] = pb[idx * 3 + 2];
        }
        __syncthreads();
        int wave = tid >> 6, lane = tid & 63;
        int g = (blk & 255) * 4 + wave;    // 0..1023
        int gidx = b * NP + g;
        float cx = newp[(size_t)gidx * 3 + 0];
        float cy = newp[(size_t)gidx * 3 + 1];
        float cz = newp[(size_t)gidx * 3 + 2];
        const float R2 = 0.01f;
        int cnt = 0, first = -1;
        for (int chunk = 0; chunk < NN / 64 && cnt < NS; ++chunk) {
            int j = chunk * 64 + lane;
            float dx = __fsub_rn(cx, sx[j]);
            float dy = __fsub_rn(cy, sy[j]);
            float dz = __fsub_rn(cz, sz[j]);
            float d2 = __fadd_rn(__fadd_rn(__fmul_rn(dx, dx), __fmul_rn(dy, dy)),
                                 __fmul_rn(dz, dz));
            unsigned long long mask = __ballot(d2 < R2);
            while (mask && cnt < NS) {
                int bit = __ffsll(mask) - 1;
                mask &= mask - 1;
                int idx = chunk * 64 + bit;
                if (first < 0) first = idx;
                if (lane == 0) nbr[(size_t)gidx * NS + cnt] = idx;
                ++cnt;
            }
        }
        if (lane == 0) {
            for (int i = cnt; i < NS; ++i) nbr[(size_t)gidx * NS + i] = first;
        }
    } else {
        // ---- GEMM1: zt[b][j][384] = Ws[384x96] @ relu(x[b][:, j]) ----
        float* xt = smem;            // [96][64]
        float* wt = smem + 6144;     // [64][97]
        int g = blockIdx.x - 2048;
        int b = g & 7;
        int t2 = g >> 3;             // 0..383
        int ob = t2 >> 6;            // 0..5
        int jt = t2 & 63;            // 0..63

        for (int idx = tid; idx < 96 * 64; idx += 256) {
            int c = idx >> 6, j = idx & 63;
            xt[c * 64 + j] = fmaxf(x[((size_t)b * CC + c) * NN + jt * 64 + j], 0.0f);
        }
        for (int idx = tid; idx < 64 * 96; idx += 256) {
            int r = idx / 96, c = idx - r * 96;
            wt[r * 97 + c] = Ws[(ob * 64 + r) * 96 + c];
        }
        __syncthreads();

        int ty = tid >> 4, tx = tid & 15;
        float acc[4][4] = {};
        for (int k = 0; k < 96; ++k) {
            float a0 = wt[(ty * 4 + 0) * 97 + k];
            float a1 = wt[(ty * 4 + 1) * 97 + k];
            float a2 = wt[(ty * 4 + 2) * 97 + k];
            float a3 = wt[(ty * 4 + 3) * 97 + k];
            float4 bv = *(const float4*)&xt[k * 64 + tx * 4];
            acc[0][0] = fmaf(a0, bv.x, acc[0][0]); acc[0][1] = fmaf(a0, bv.y, acc[0][1]);
            acc[0][2] = fmaf(a0, bv.z, acc[0][2]); acc[0][3] = fmaf(a0, bv.w, acc[0][3]);
            acc[1][0] = fmaf(a1, bv.x, acc[1][0]); acc[1][1] = fmaf(a1, bv.y, acc[1][1]);
            acc[1][2] = fmaf(a1, bv.z, acc[1][2]); acc[1][3] = fmaf(a1, bv.w, acc[1][3]);
            acc[2][0] = fmaf(a2, bv.x, acc[2][0]); acc[2][1] = fmaf(a2, bv.y, acc[2][1]);
            acc[2][2] = fmaf(a2, bv.z, acc[2][2]); acc[2][3] = fmaf(a2, bv.w, acc[2][3]);
            acc[3][0] = fmaf(a3, bv.x, acc[3][0]); acc[3][1] = fmaf(a3, bv.y, acc[3][1]);
            acc[3][2] = fmaf(a3, bv.z, acc[3][2]); acc[3][3] = fmaf(a3, bv.w, acc[3][3]);
        }
        for (int jj = 0; jj < 4; ++jj) {
            int j = jt * 64 + tx * 4 + jj;
            float4 v = make_float4(acc[0][jj], acc[1][jj], acc[2][jj], acc[3][jj]);
            *(float4*)&zt[((size_t)b * NN + j) * 384 + ob * 64 + ty * 4] = v;
        }
    }
}

// ---------------------------------------------------------------------------
// Fused: gather zc+zn, +beta -> relu, sin/cos pos embed, agg=(t+1)*emb,
// max+mean pool, relu, 192x192 conv2 (BN folded) -> relu -> f32 store.
// ---------------------------------------------------------------------------
__global__ __launch_bounds__(192) void fused_kernel(const float* __restrict__ p,
                                                    const float* __restrict__ newp,
                                                    const int* __restrict__ samp,
                                                    const int* __restrict__ nbr,
                                                    const float* __restrict__ zt,
                                                    const float* __restrict__ beta1,
                                                    const float* __restrict__ WcT,
                                                    const float* __restrict__ beta2,
                                                    float* __restrict__ out) {
    int blk = blockIdx.x;
    int b = blk >> 10, g = blk & 1023;
    int tid = threadIdx.x;
    __shared__ float dp[3][NS];
    __shared__ int nb[NS];
    __shared__ float pl[C2];

    if (tid < NS) {
        int j = nbr[(size_t)blk * NS + tid];
        nb[tid] = j;
        dp[0][tid] = p[((size_t)b * NN + j) * 3 + 0] - newp[(size_t)blk * 3 + 0];
        dp[1][tid] = p[((size_t)b * NN + j) * 3 + 1] - newp[(size_t)blk * 3 + 1];
        dp[2][tid] = p[((size_t)b * NN + j) * 3 + 2] - newp[(size_t)blk * 3 + 2];
    }
    __syncthreads();

    int o = tid;
    int sidx = samp[blk];
    float zc = zt[((size_t)b * NN + sidx) * 384 + o];
    float bet = beta1[o];
    int axis = o >> 6;        // 0..2
    int k = o & 63;
    int kk = (k < 32) ? k : k - 32;
    float dim = powf(500.0f, (float)kk * (1.0f / 32.0f));

    float mx = -3.4e38f, sm = 0.0f;
    for (int s = 0; s < NS; ++s) {
        float zn = zt[((size_t)b * NN + nb[s]) * 384 + C2 + o];
        float t = fmaxf(zc + zn + bet, 0.0f);
        float pos = (50.0f * dp[axis][s]) / dim;
        float e = (k < 32) ? sinf(pos) : cosf(pos);
        float a = fmaf(t, e, e);          // xj*emb + emb
        mx = fmaxf(mx, a);
        sm += a;
    }
    pl[o] = fmaxf(mx + sm * (1.0f / 16.0f), 0.0f);
    __syncthreads();

    float acc = 0.0f;
    for (int c = 0; c < C2; ++c) acc = fmaf(WcT[c * C2 + o], pl[c], acc);
    float res = fmaxf(acc + beta2[o], 0.0f);
    out[BB * NP * 3 + ((size_t)b * C2 + o) * NP + g] = res;
}

// ---------------------------------------------------------------------------
extern "C" void kernel_launch(void* const* d_in, const int* in_sizes, int n_in,
                              void* d_out, int out_size, void* d_ws, size_t ws_size,
                              hipStream_t stream) {
    (void)in_sizes; (void)n_in; (void)out_size; (void)ws_size;
    const float* p  = (const float*)d_in[0];
    const float* x  = (const float*)d_in[1];
    const float* Wt = (const float*)d_in[2];
    const float* gt = (const float*)d_in[3];
    const float* bt = (const float*)d_in[4];
    const float* mt = (const float*)d_in[5];
    const float* vt = (const float*)d_in[6];
    const float* Wc = (const float*)d_in[7];
    const float* gc = (const float*)d_in[8];
    const float* bc = (const float*)d_in[9];
    const float* mc = (const float*)d_in[10];
    const float* vc = (const float*)d_in[11];
    float* out = (float*)d_out;              // f32 output (reference is all-f32)
    char* ws = (char*)d_ws;

    int*   samp  = (int*)(ws + SAMP_OFF);
    int*   nbr   = (int*)(ws + NBR_OFF);
    float* Ws    = (float*)(ws + WSW_OFF);
    float* beta1 = (float*)(ws + B1_OFF);
    float* WcT   = (float*)(ws + WCT_OFF);
    float* beta2 = (float*)(ws + B2_OFF);
    float* zt    = (float*)(ws + ZT_OFF);
    const float* newp = out;                 // new_p lives in d_out[0 .. 24576)

    fps_prep_kernel<<<dim3(BB + 145), dim3(256), 0, stream>>>(
        p, Wt, gt, bt, mt, vt, Wc, gc, bc, mc, vc,
        Ws, beta1, WcT, beta2, samp, out);
    bq_gemm_kernel<<<dim3(2048 + 3072), dim3(256), 0, stream>>>(
        p, newp, nbr, x, Ws, zt);
    fused_kernel<<<dim3(BB * NP), dim3(192), 0, stream>>>(
        p, newp, samp, nbr, zt, beta1, WcT, beta2, out);
}